// Round 2
// baseline (1382.616 us; speedup 1.0000x reference)
//
#include <hip/hip_runtime.h>
#include <hip/hip_bf16.h>

#define VOCAB 100
#define EDIM  128
#define HDIM  256
#define LDIM  64
#define G3    768      // 3*H
#define TT    128
#define BB    4096
#define LROW  (TT * VOCAB)   // 12800 floats per batch row of logits

typedef float f32x4  __attribute__((ext_vector_type(4)));
typedef short bf16x8 __attribute__((ext_vector_type(8)));

__device__ __forceinline__ short f2bf(float f) {
    unsigned u = __builtin_bit_cast(unsigned, f);
    u += 0x7FFFu + ((u >> 16) & 1u);           // round-to-nearest-even
    return (short)(u >> 16);
}
__device__ __forceinline__ float bf2f(short s) {
    unsigned u = ((unsigned)(unsigned short)s) << 16;
    return __builtin_bit_cast(float, u);
}
__device__ __forceinline__ float sigf(float x)   { return 1.0f / (1.0f + __expf(-x)); }
__device__ __forceinline__ float tanh_f(float x) { return 2.0f / (1.0f + __expf(-2.0f * x)) - 1.0f; }

// ---------------- prep: PT[v][g] = enc_Wih @ embedding[v] + enc_bih ----------------
__global__ void pt_kernel(const float* __restrict__ emb, const float* __restrict__ Wih,
                          const float* __restrict__ bih, float* __restrict__ PT) {
    int v = blockIdx.x;
    __shared__ float se[EDIM];
    for (int e = threadIdx.x; e < EDIM; e += blockDim.x) se[e] = emb[v * EDIM + e];
    __syncthreads();
    for (int g = threadIdx.x; g < G3; g += blockDim.x) {
        const float* wr = Wih + g * EDIM;
        float acc = bih[g];
        #pragma unroll 8
        for (int e = 0; e < EDIM; ++e) acc += se[e] * wr[e];
        PT[v * G3 + g] = acc;
    }
}

#define HP_LD 772                 // f32 cols (768 + 4 pad)
#define H_LDS 264                 // bf16 cols (256 + 8 pad)

// ===================================================================
// ENCODER: 256 blocks x 512 thr, 16 batch rows/block.
// W_hh register-resident (bf16 frags). h kept as hi/lo bf16 pair in LDS.
// h_last stashed into out[] logits region (fully overwritten by decoder).
// ===================================================================
#define E_SM_HP   0
#define E_SM_HHI  (16 * HP_LD * 4)                 // 49408
#define E_SM_HLO  (E_SM_HHI + 16 * H_LDS * 2)      // +8448
#define E_SM_TOK  (E_SM_HLO + 16 * H_LDS * 2)      // +8448
#define E_SM_TOT  (E_SM_TOK + 16 * TT * 4)         // +8192 = 74496

__global__ __launch_bounds__(512, 2) void enc_kernel(
    const int* __restrict__ x, const float* __restrict__ PT,
    const float* __restrict__ enc_Whh, const float* __restrict__ enc_bhh,
    float* __restrict__ out)
{
    __shared__ __attribute__((aligned(16))) unsigned char smem[E_SM_TOT];
    float* s_hp  = (float*)(smem + E_SM_HP);
    short* s_hhi = (short*)(smem + E_SM_HHI);
    short* s_hlo = (short*)(smem + E_SM_HLO);
    int*   s_tok = (int*)  (smem + E_SM_TOK);

    const int tid  = threadIdx.x;
    const int lane = tid & 63;
    const int wv   = tid >> 6;
    const int l15  = lane & 15;
    const int lgrp = lane >> 4;
    const int bbase = blockIdx.x * 16;
    const int gc  = tid & 255;
    const int gm2 = tid >> 8;

    for (int i = tid; i < 16 * TT; i += 512) s_tok[i] = x[bbase * TT + i];

    bf16x8 Wreg[6][8];
    #pragma unroll
    for (int nt = 0; nt < 6; ++nt) {
        #pragma unroll
        for (int ks = 0; ks < 8; ++ks) {
            const float* p = enc_Whh + (wv * 96 + nt * 16 + l15) * HDIM + ks * 32 + lgrp * 8;
            float4 f0 = *(const float4*)p;
            float4 f1 = *(const float4*)(p + 4);
            bf16x8 w;
            w[0]=f2bf(f0.x); w[1]=f2bf(f0.y); w[2]=f2bf(f0.z); w[3]=f2bf(f0.w);
            w[4]=f2bf(f1.x); w[5]=f2bf(f1.y); w[6]=f2bf(f1.z); w[7]=f2bf(f1.w);
            Wreg[nt][ks] = w;
        }
    }

    const float bhr = enc_bhh[gc], bhz = enc_bhh[gc + 256], bhn = enc_bhh[gc + 512];

    const f32x4 z4 = {0.f, 0.f, 0.f, 0.f};
    float hst[8];
    #pragma unroll
    for (int i = 0; i < 8; ++i) hst[i] = 0.0f;
    #pragma unroll
    for (int i = 0; i < 8; ++i) {
        int m = gm2 + 2 * i;
        s_hhi[m * H_LDS + gc] = 0;
        s_hlo[m * H_LDS + gc] = 0;
    }

    #pragma unroll 1
    for (int t = 0; t < TT; ++t) {
        __syncthreads();                       // h_hi/h_lo ready
        f32x4 acc[6];
        #pragma unroll
        for (int nt = 0; nt < 6; ++nt) acc[nt] = z4;
        #pragma unroll
        for (int ks = 0; ks < 8; ++ks) {
            const int aoff = l15 * H_LDS + ks * 32 + lgrp * 8;
            bf16x8 a = *(const bf16x8*)(s_hhi + aoff);
            #pragma unroll
            for (int nt = 0; nt < 6; ++nt)
                acc[nt] = __builtin_amdgcn_mfma_f32_16x16x32_bf16(a, Wreg[nt][ks], acc[nt], 0, 0, 0);
            a = *(const bf16x8*)(s_hlo + aoff);
            #pragma unroll
            for (int nt = 0; nt < 6; ++nt)
                acc[nt] = __builtin_amdgcn_mfma_f32_16x16x32_bf16(a, Wreg[nt][ks], acc[nt], 0, 0, 0);
        }
        #pragma unroll
        for (int nt = 0; nt < 6; ++nt) {
            int col = wv * 96 + nt * 16 + l15;
            #pragma unroll
            for (int j = 0; j < 4; ++j) s_hp[(lgrp * 4 + j) * HP_LD + col] = acc[nt][j];
        }
        __syncthreads();                       // hp ready
        #pragma unroll
        for (int i = 0; i < 8; ++i) {
            int m = gm2 + 2 * i;
            int tok = s_tok[m * TT + t];
            const float* pt = PT + tok * G3;
            float xr = pt[gc], xz = pt[gc + 256], xn = pt[gc + 512];
            float hr = s_hp[m * HP_LD + gc]       + bhr;
            float hz = s_hp[m * HP_LD + gc + 256] + bhz;
            float hn = s_hp[m * HP_LD + gc + 512] + bhn;
            float r  = sigf(xr + hr), zg = sigf(xz + hz);
            float n  = tanh_f(xn + r * hn);
            float h  = (1.0f - zg) * n + zg * hst[i];
            hst[i] = h;
            short hi = f2bf(h);
            s_hhi[m * H_LDS + gc] = hi;
            s_hlo[m * H_LDS + gc] = f2bf(h - bf2f(hi));
        }
    }
    // stash h_last into out[] logits region (row r occupies out[r*LROW ..]; decoder
    // reads its own rows before writing them)
    #pragma unroll
    for (int i = 0; i < 8; ++i) {
        int m = gm2 + 2 * i;
        out[(size_t)(bbase + m) * LROW + gc] = hst[i];
    }
}

// ===================================================================
// DECODER: 256 blocks x 512 thr. mu/lv/z epilogue + 128-step GRU +
// fused vocab projection.
// ===================================================================
#define D_SM_HP   0
#define D_SM_HBF  (16 * HP_LD * 4)                  // 49408
#define D_SM_OUTW (D_SM_HBF + 16 * H_LDS * 2)       // +8448
#define D_SM_ZP   (D_SM_OUTW + VOCAB * 512)         // +51200
#define D_SM_TOT  (D_SM_ZP + 16 * G3 * 4)           // +49152 = 158208

__global__ __launch_bounds__(512, 2) void dec_kernel(
    const float* __restrict__ eps,
    const float* __restrict__ mu_W, const float* __restrict__ mu_b,
    const float* __restrict__ lv_W, const float* __restrict__ lv_b,
    const float* __restrict__ di_W, const float* __restrict__ di_b,
    const float* __restrict__ dec_Wih, const float* __restrict__ dec_Whh,
    const float* __restrict__ dec_bih, const float* __restrict__ dec_bhh,
    const float* __restrict__ out_W, const float* __restrict__ out_b,
    float* __restrict__ out)
{
    __shared__ __attribute__((aligned(16))) unsigned char smem[D_SM_TOT];
    float* s_hp  = (float*)(smem + D_SM_HP);
    short* s_hbf = (short*)(smem + D_SM_HBF);
    unsigned char* s_outw = smem + D_SM_OUTW;
    float* s_zp  = (float*)(smem + D_SM_ZP);

    const int tid  = threadIdx.x;
    const int lane = tid & 63;
    const int wv   = tid >> 6;
    const int l15  = lane & 15;
    const int lgrp = lane >> 4;
    const int bbase = blockIdx.x * 16;
    const int gc  = tid & 255;
    const int gm2 = tid >> 8;

    // load h_last tile (stashed by encoder in out[])
    for (int i = tid; i < 16 * HDIM; i += 512) {
        int m = i >> 8, c = i & 255;
        s_hp[m * HP_LD + c] = out[(size_t)(bbase + m) * LROW + c];
    }

    // decoder recurrent weights -> registers (overlaps with epilogue below)
    bf16x8 Wreg[6][8];
    #pragma unroll
    for (int nt = 0; nt < 6; ++nt) {
        #pragma unroll
        for (int ks = 0; ks < 8; ++ks) {
            const float* p = dec_Whh + (wv * 96 + nt * 16 + l15) * HDIM + ks * 32 + lgrp * 8;
            float4 f0 = *(const float4*)p;
            float4 f1 = *(const float4*)(p + 4);
            bf16x8 w;
            w[0]=f2bf(f0.x); w[1]=f2bf(f0.y); w[2]=f2bf(f0.z); w[3]=f2bf(f0.w);
            w[4]=f2bf(f1.x); w[5]=f2bf(f1.y); w[6]=f2bf(f1.z); w[7]=f2bf(f1.w);
            Wreg[nt][ks] = w;
        }
    }
    __syncthreads();

    // ---- mu / logvar / z (2 output slots per thread) ----
    float z0 = 0.f, z1 = 0.f;
    {
        const size_t MU_OFF = (size_t)BB * TT * VOCAB;
        const size_t LV_OFF = MU_OFF + (size_t)BB * LDIM;
        #pragma unroll
        for (int oo = 0; oo < 2; ++oo) {
            int o = tid * 2 + oo;
            int m = o >> 6, j = o & 63;
            const float* mwr = mu_W + j * HDIM;
            const float* lwr = lv_W + j * HDIM;
            float am = mu_b[j], al = lv_b[j];
            #pragma unroll 4
            for (int k = 0; k < HDIM; ++k) { float hv = s_hp[m * HP_LD + k]; am += hv * mwr[k]; al += hv * lwr[k]; }
            size_t bo = (size_t)(bbase + m) * LDIM + j;
            out[MU_OFF + bo] = am;
            out[LV_OFF + bo] = al;
            float zv = am + eps[bo] * __expf(0.5f * al);
            if (oo == 0) z0 = zv; else z1 = zv;
        }
    }
    __syncthreads();                    // all reads of h_last done
    {   // write z into s_hp rows (cols 0..63); stage out_W -> swizzled LDS bf16
        int o0 = tid * 2;
        s_hp[(o0 >> 6) * HP_LD + (o0 & 63)] = z0;
        int o1 = tid * 2 + 1;
        s_hp[(o1 >> 6) * HP_LD + (o1 & 63)] = z1;
        for (int idx = tid; idx < VOCAB * HDIM; idx += 512) {
            int r = idx >> 8, k = idx & 255;
            *(short*)(s_outw + r * 512 + ((2 * k) ^ ((r & 7) << 4))) = f2bf(out_W[idx]);
        }
    }
    __syncthreads();                    // z + out_W staged
    float hst[8];
    {   // hidden = tanh(di_W z + di_b); zp = dec_Wih z + dec_bih
        float ah[8], ar[8], az[8], an[8];
        float dib = di_b[gc];
        float bir = dec_bih[gc], biz = dec_bih[gc + 256], bin_ = dec_bih[gc + 512];
        #pragma unroll
        for (int i = 0; i < 8; ++i) { ah[i] = dib; ar[i] = bir; az[i] = biz; an[i] = bin_; }
        const float* w0 = di_W + gc * LDIM;
        const float* w1 = dec_Wih + gc * LDIM;
        const float* w2 = dec_Wih + (gc + 256) * LDIM;
        const float* w3 = dec_Wih + (gc + 512) * LDIM;
        #pragma unroll 2
        for (int j = 0; j < LDIM; ++j) {
            float a0 = w0[j], a1 = w1[j], a2 = w2[j], a3 = w3[j];
            #pragma unroll
            for (int i = 0; i < 8; ++i) {
                float zv = s_hp[(gm2 + 2 * i) * HP_LD + j];
                ah[i] += zv * a0; ar[i] += zv * a1; az[i] += zv * a2; an[i] += zv * a3;
            }
        }
        #pragma unroll
        for (int i = 0; i < 8; ++i) {
            int m = gm2 + 2 * i;
            float th = tanh_f(ah[i]);
            hst[i] = th;
            s_zp[m * G3 + gc]       = ar[i];
            s_zp[m * G3 + gc + 256] = az[i];
            s_zp[m * G3 + gc + 512] = an[i];
            s_hbf[m * H_LDS + gc] = f2bf(th);
        }
    }
    const float bhr = dec_bhh[gc], bhz = dec_bhh[gc + 256], bhn = dec_bhh[gc + 512];
    const int vcol = wv * 16 + l15;
    const int orow = (vcol < VOCAB) ? vcol : (VOCAB - 1);
    float ob = 0.0f;
    if (wv < 7 && vcol < VOCAB) ob = out_b[vcol];
    const f32x4 z4 = {0.f, 0.f, 0.f, 0.f};

    #pragma unroll 1
    for (int t = 0; t < TT; ++t) {
        __syncthreads();                       // h_bf (= h_t) ready
        f32x4 acc[6];
        #pragma unroll
        for (int nt = 0; nt < 6; ++nt) acc[nt] = z4;
        f32x4 aco = z4;
        const bool doOut = (t > 0) && (wv < 7);
        #pragma unroll
        for (int ks = 0; ks < 8; ++ks) {
            bf16x8 a = *(const bf16x8*)(s_hbf + l15 * H_LDS + ks * 32 + lgrp * 8);
            #pragma unroll
            for (int nt = 0; nt < 6; ++nt)
                acc[nt] = __builtin_amdgcn_mfma_f32_16x16x32_bf16(a, Wreg[nt][ks], acc[nt], 0, 0, 0);
            if (doOut) {
                bf16x8 wo = *(const bf16x8*)(s_outw + orow * 512 + ((ks * 64 + lgrp * 16) ^ ((orow & 7) << 4)));
                aco = __builtin_amdgcn_mfma_f32_16x16x32_bf16(a, wo, aco, 0, 0, 0);
            }
        }
        if (doOut && vcol < VOCAB) {           // logits[:, t-1, :] from h_t
            size_t base = (size_t)(bbase + lgrp * 4) * LROW + (size_t)(t - 1) * VOCAB + vcol;
            #pragma unroll
            for (int j = 0; j < 4; ++j) out[base + (size_t)j * LROW] = aco[j] + ob;
        }
        #pragma unroll
        for (int nt = 0; nt < 6; ++nt) {
            int col = wv * 96 + nt * 16 + l15;
            #pragma unroll
            for (int j = 0; j < 4; ++j) s_hp[(lgrp * 4 + j) * HP_LD + col] = acc[nt][j];
        }
        __syncthreads();                       // hp ready
        #pragma unroll
        for (int i = 0; i < 8; ++i) {
            int m = gm2 + 2 * i;
            float xr = s_zp[m * G3 + gc], xz = s_zp[m * G3 + gc + 256], xn = s_zp[m * G3 + gc + 512];
            float hr = s_hp[m * HP_LD + gc]       + bhr;
            float hz = s_hp[m * HP_LD + gc + 256] + bhz;
            float hn = s_hp[m * HP_LD + gc + 512] + bhn;
            float r  = sigf(xr + hr), zg = sigf(xz + hz);
            float n  = tanh_f(xn + r * hn);
            float h  = (1.0f - zg) * n + zg * hst[i];
            hst[i] = h;
            s_hbf[m * H_LDS + gc] = f2bf(h);
        }
    }
    // final vocab projection: logits[:, 127, :] from h_128
    __syncthreads();
    if (wv < 7) {
        f32x4 aco = z4;
        #pragma unroll
        for (int ks = 0; ks < 8; ++ks) {
            bf16x8 a  = *(const bf16x8*)(s_hbf + l15 * H_LDS + ks * 32 + lgrp * 8);
            bf16x8 wo = *(const bf16x8*)(s_outw + orow * 512 + ((ks * 64 + lgrp * 16) ^ ((orow & 7) << 4)));
            aco = __builtin_amdgcn_mfma_f32_16x16x32_bf16(a, wo, aco, 0, 0, 0);
        }
        if (vcol < VOCAB) {
            size_t base = (size_t)(bbase + lgrp * 4) * LROW + (size_t)(TT - 1) * VOCAB + vcol;
            #pragma unroll
            for (int j = 0; j < 4; ++j) out[base + (size_t)j * LROW] = aco[j] + ob;
        }
    }
}

extern "C" void kernel_launch(void* const* d_in, const int* in_sizes, int n_in,
                              void* d_out, int out_size, void* d_ws, size_t ws_size,
                              hipStream_t stream) {
    const int*   x       = (const int*)  d_in[0];
    const float* eps     = (const float*)d_in[1];
    const float* emb     = (const float*)d_in[2];
    const float* enc_Wih = (const float*)d_in[3];
    const float* enc_Whh = (const float*)d_in[4];
    const float* enc_bih = (const float*)d_in[5];
    const float* enc_bhh = (const float*)d_in[6];
    const float* mu_W    = (const float*)d_in[7];
    const float* mu_b    = (const float*)d_in[8];
    const float* lv_W    = (const float*)d_in[9];
    const float* lv_b    = (const float*)d_in[10];
    const float* di_W    = (const float*)d_in[11];
    const float* di_b    = (const float*)d_in[12];
    const float* dec_Wih = (const float*)d_in[13];
    const float* dec_Whh = (const float*)d_in[14];
    const float* dec_bih = (const float*)d_in[15];
    const float* dec_bhh = (const float*)d_in[16];
    const float* out_W   = (const float*)d_in[17];
    const float* out_b   = (const float*)d_in[18];
    float* out = (float*)d_out;
    float* PT  = (float*)d_ws;   // [100][768] f32 = 307200 B

    pt_kernel<<<VOCAB, 256, 0, stream>>>(emb, enc_Wih, enc_bih, PT);
    enc_kernel<<<BB / 16, 512, 0, stream>>>(x, PT, enc_Whh, enc_bhh, out);
    dec_kernel<<<BB / 16, 512, 0, stream>>>(eps, mu_W, mu_b, lv_W, lv_b,
        di_W, di_b, dec_Wih, dec_Whh, dec_bih, dec_bhh, out_W, out_b, out);
}

// Round 3
// 1282.322 us; speedup vs baseline: 1.0782x; 1.0782x over previous
//
#include <hip/hip_runtime.h>
#include <hip/hip_bf16.h>

#define VOCAB 100
#define EDIM  128
#define HDIM  256
#define LDIM  64
#define G3    768
#define TT    128
#define BB    4096
#define LROW  (TT * VOCAB)
#define H_LD  264            // shorts per row in h buffers (256 + 8 pad)
#define HBUF  (16 * H_LD)
#define HL_LD 260            // floats per row in dec f32 scratch

typedef float f32x4  __attribute__((ext_vector_type(4)));
typedef short bf16x8 __attribute__((ext_vector_type(8)));
typedef short short4v __attribute__((ext_vector_type(4)));

__device__ __forceinline__ short f2bf(float f) {
    unsigned u = __builtin_bit_cast(unsigned, f);
    u += 0x7FFFu + ((u >> 16) & 1u);
    return (short)(u >> 16);
}
__device__ __forceinline__ float bf2f(short s) {
    unsigned u = ((unsigned)(unsigned short)s) << 16;
    return __builtin_bit_cast(float, u);
}
__device__ __forceinline__ float sigf(float x)   { return 1.0f / (1.0f + __expf(-x)); }
__device__ __forceinline__ float tanh_f(float x) { return 2.0f / (1.0f + __expf(-2.0f * x)) - 1.0f; }

// B-fragment loader for the K-permuted h layout:
// physical k (what A holds) maps to logical k_log = (k&~31) | ((k&1)<<4) | ((k&31)>>1)
// lane(l15=outcol, lgrp) element e: k_phys = ks*32+lgrp*8+e
//   -> k_log = ks*32 + (e&1)*16 + lgrp*4 + (e>>1)
__device__ __forceinline__ bf16x8 load_bfragK(const float* __restrict__ W, int outcol, int ks, int lgrp) {
    const float* p = W + outcol * HDIM + ks * 32 + lgrp * 4;
    float4 f0 = *(const float4*)p;
    float4 f1 = *(const float4*)(p + 16);
    bf16x8 w;
    w[0] = f2bf(f0.x); w[1] = f2bf(f1.x); w[2] = f2bf(f0.y); w[3] = f2bf(f1.y);
    w[4] = f2bf(f0.z); w[5] = f2bf(f1.z); w[6] = f2bf(f0.w); w[7] = f2bf(f1.w);
    return w;
}

// ---------------- prep: PT2[v][g] = enc_Wih @ emb[v] + enc_bih + (g<512 ? enc_bhh : 0) ----------------
__global__ void pt_kernel(const float* __restrict__ emb, const float* __restrict__ Wih,
                          const float* __restrict__ bih, const float* __restrict__ bhh,
                          float* __restrict__ PT) {
    int v = blockIdx.x;
    __shared__ float se[EDIM];
    for (int e = threadIdx.x; e < EDIM; e += blockDim.x) se[e] = emb[v * EDIM + e];
    __syncthreads();
    for (int g = threadIdx.x; g < G3; g += blockDim.x) {
        const float* wr = Wih + g * EDIM;
        float acc = bih[g] + (g < 512 ? bhh[g] : 0.0f);
        #pragma unroll 8
        for (int e = 0; e < EDIM; ++e) acc += se[e] * wr[e];
        PT[v * G3 + g] = acc;
    }
}

// ===================================================================
// ENCODER: in-register gates, 1 barrier/step, hi/lo bf16 h.
// ===================================================================
__global__ __launch_bounds__(512, 2) void enc_kernel(
    const int* __restrict__ x, const float* __restrict__ PT2,
    const float* __restrict__ Whh, const float* __restrict__ bhh,
    float* __restrict__ out)
{
    __shared__ short s_h[2][2][HBUF];      // [buf][hi/lo]
    __shared__ int s_tok[16 * TT];

    const int tid  = threadIdx.x;
    const int lane = tid & 63;
    const int wv   = tid >> 6;
    const int l15  = lane & 15;
    const int lgrp = lane >> 4;
    const int bbase = blockIdx.x * 16;
    const int colb = wv * 32 + l15;        // logical col for cg=0; cg=1 is +16

    for (int i = tid; i < 16 * TT; i += 512) s_tok[i] = x[bbase * TT + i];

    bf16x8 Wreg[3][2][8];
    #pragma unroll
    for (int g = 0; g < 3; ++g)
        #pragma unroll
        for (int cg = 0; cg < 2; ++cg)
            #pragma unroll
            for (int ks = 0; ks < 8; ++ks)
                Wreg[g][cg][ks] = load_bfragK(Whh, g * 256 + colb + cg * 16, ks, lgrp);

    const float bhn0 = bhh[512 + colb];
    const float bhn1 = bhh[528 + colb];

    for (int i = tid; i < 2 * HBUF; i += 512) s_h[0][0][i] = 0;   // zero buf0 hi+lo
    __syncthreads();

    const f32x4 z4 = {0.f, 0.f, 0.f, 0.f};

    #pragma unroll 1
    for (int t = 0; t < TT; ++t) {
        const short* rh = s_h[t & 1][0];
        const short* rl = s_h[t & 1][1];
        short* wh = s_h[(t + 1) & 1][0];
        short* wl = s_h[(t + 1) & 1][1];

        f32x4 acc[3][2];
        #pragma unroll
        for (int g = 0; g < 3; ++g) { acc[g][0] = z4; acc[g][1] = z4; }

        #pragma unroll
        for (int ks = 0; ks < 8; ++ks) {
            const int aoff = l15 * H_LD + ks * 32 + lgrp * 8;
            bf16x8 ahi = *(const bf16x8*)(rh + aoff);
            bf16x8 alo = *(const bf16x8*)(rl + aoff);
            #pragma unroll
            for (int g = 0; g < 3; ++g) {
                acc[g][0] = __builtin_amdgcn_mfma_f32_16x16x32_bf16(ahi, Wreg[g][0][ks], acc[g][0], 0, 0, 0);
                acc[g][1] = __builtin_amdgcn_mfma_f32_16x16x32_bf16(ahi, Wreg[g][1][ks], acc[g][1], 0, 0, 0);
            }
            #pragma unroll
            for (int g = 0; g < 3; ++g) {
                acc[g][0] = __builtin_amdgcn_mfma_f32_16x16x32_bf16(alo, Wreg[g][0][ks], acc[g][0], 0, 0, 0);
                acc[g][1] = __builtin_amdgcn_mfma_f32_16x16x32_bf16(alo, Wreg[g][1][ks], acc[g][1], 0, 0, 0);
            }
        }

        #pragma unroll
        for (int j = 0; j < 4; ++j) {
            const int row = lgrp * 4 + j;
            const int tok = s_tok[row * TT + t];
            const float* p = PT2 + tok * G3 + colb;
            const int hoff = row * H_LD + wv * 32 + 2 * l15;
            unsigned hpi = *(const unsigned*)(rh + hoff);
            unsigned hpl = *(const unsigned*)(rl + hoff);
            float hp0 = bf2f((short)(hpi & 0xFFFF)) + bf2f((short)(hpl & 0xFFFF));
            float hp1 = bf2f((short)(hpi >> 16))    + bf2f((short)(hpl >> 16));
            unsigned whi = 0, wlo = 0;
            #pragma unroll
            for (int cg = 0; cg < 2; ++cg) {
                float xr = p[cg * 16], xz = p[256 + cg * 16], xn = p[512 + cg * 16];
                float rg = sigf(acc[0][cg][j] + xr);
                float zg = sigf(acc[1][cg][j] + xz);
                float hn = acc[2][cg][j] + (cg ? bhn1 : bhn0);
                float n  = tanh_f(xn + rg * hn);
                float hpv = cg ? hp1 : hp0;
                float h  = (1.0f - zg) * n + zg * hpv;
                if (t == TT - 1) out[(size_t)(bbase + row) * LROW + colb + cg * 16] = h;
                unsigned hhi = (unsigned)(unsigned short)f2bf(h);
                float rem = h - bf2f((short)hhi);
                unsigned hlo = (unsigned)(unsigned short)f2bf(rem);
                whi |= hhi << (16 * cg);
                wlo |= hlo << (16 * cg);
            }
            *(unsigned*)(wh + hoff) = whi;
            *(unsigned*)(wl + hoff) = wlo;
        }
        __syncthreads();
    }
}

// ===================================================================
// DECODER: prologue (mu/lv/z/zp/hidden) + in-register-gate GRU +
// fused vocab projection. 1 barrier/step.
// ===================================================================
__global__ __launch_bounds__(512, 2) void dec_kernel(
    const float* __restrict__ eps,
    const float* __restrict__ mu_W, const float* __restrict__ mu_b,
    const float* __restrict__ lv_W, const float* __restrict__ lv_b,
    const float* __restrict__ di_W, const float* __restrict__ di_b,
    const float* __restrict__ dec_Wih, const float* __restrict__ dec_Whh,
    const float* __restrict__ dec_bih, const float* __restrict__ dec_bhh,
    const float* __restrict__ out_W, const float* __restrict__ out_b,
    float* __restrict__ out)
{
    __shared__ float s_hl[16 * HL_LD];                       // 16640 B
    __shared__ short s_zp4[16 * 256 * 4];                    // 32768 B, {r,z,n,bhn} bf16
    __shared__ __attribute__((aligned(16))) unsigned char s_outw[VOCAB * 512]; // 51200 B
    __shared__ short s_h[2][HBUF];                           // 16896 B

    const int tid  = threadIdx.x;
    const int lane = tid & 63;
    const int wv   = tid >> 6;
    const int l15  = lane & 15;
    const int lgrp = lane >> 4;
    const int bbase = blockIdx.x * 16;
    const int colb = wv * 32 + l15;
    const int gc  = tid & 255;
    const int gm2 = tid >> 8;

    // h_last stash -> LDS
    for (int i = tid; i < 16 * HDIM; i += 512) {
        int m = i >> 8, c = i & 255;
        s_hl[m * HL_LD + c] = out[(size_t)(bbase + m) * LROW + c];
    }

    bf16x8 Wreg[3][2][8];
    #pragma unroll
    for (int g = 0; g < 3; ++g)
        #pragma unroll
        for (int cg = 0; cg < 2; ++cg)
            #pragma unroll
            for (int ks = 0; ks < 8; ++ks)
                Wreg[g][cg][ks] = load_bfragK(dec_Whh, g * 256 + colb + cg * 16, ks, lgrp);
    __syncthreads();

    // ---- mu / logvar / z ----
    float z0 = 0.f, z1 = 0.f;
    {
        const size_t MU_OFF = (size_t)BB * TT * VOCAB;
        const size_t LV_OFF = MU_OFF + (size_t)BB * LDIM;
        #pragma unroll
        for (int oo = 0; oo < 2; ++oo) {
            int o = tid * 2 + oo;
            int m = o >> 6, j = o & 63;
            const float* mwr = mu_W + j * HDIM;
            const float* lwr = lv_W + j * HDIM;
            float am = mu_b[j], al = lv_b[j];
            #pragma unroll 4
            for (int k = 0; k < HDIM; ++k) { float hv = s_hl[m * HL_LD + k]; am += hv * mwr[k]; al += hv * lwr[k]; }
            size_t bo = (size_t)(bbase + m) * LDIM + j;
            out[MU_OFF + bo] = am;
            out[LV_OFF + bo] = al;
            float zv = am + eps[bo] * __expf(0.5f * al);
            if (oo == 0) z0 = zv; else z1 = zv;
        }
    }
    __syncthreads();                       // all h_last reads done
    {
        int o0 = tid * 2;
        s_hl[(o0 >> 6) * HL_LD + (o0 & 63)] = z0;
        int o1 = o0 + 1;
        s_hl[(o1 >> 6) * HL_LD + (o1 & 63)] = z1;
        // stage out_W: K-permuted + XOR-swizzled bf16
        for (int idx = tid; idx < VOCAB * HDIM; idx += 512) {
            int r = idx >> 8, kp = idx & 255;
            int kl = (kp & ~31) | ((kp & 1) << 4) | ((kp & 31) >> 1);
            *(short*)(s_outw + r * 512 + ((2 * kp) ^ ((r & 7) << 4))) = f2bf(out_W[r * 256 + kl]);
        }
    }
    __syncthreads();                       // z + out_W staged

    float th[8], arr[8], azz[8], ann[8];
    {
        float ah[8];
        float dib = di_b[gc];
        float bir = dec_bih[gc], biz = dec_bih[gc + 256], bin_ = dec_bih[gc + 512];
        #pragma unroll
        for (int i = 0; i < 8; ++i) { ah[i] = dib; arr[i] = bir; azz[i] = biz; ann[i] = bin_; }
        const float* w0 = di_W + gc * LDIM;
        const float* w1 = dec_Wih + gc * LDIM;
        const float* w2 = dec_Wih + (gc + 256) * LDIM;
        const float* w3 = dec_Wih + (gc + 512) * LDIM;
        #pragma unroll 2
        for (int j = 0; j < LDIM; ++j) {
            float a0 = w0[j], a1 = w1[j], a2 = w2[j], a3 = w3[j];
            #pragma unroll
            for (int i = 0; i < 8; ++i) {
                float zv = s_hl[(gm2 + 2 * i) * HL_LD + j];
                ah[i] += zv * a0; arr[i] += zv * a1; azz[i] += zv * a2; ann[i] += zv * a3;
            }
        }
        float bhr = dec_bhh[gc], bhz = dec_bhh[gc + 256];
        #pragma unroll
        for (int i = 0; i < 8; ++i) {
            th[i] = tanh_f(ah[i]);
            arr[i] += bhr;
            azz[i] += bhz;
        }
    }
    __syncthreads();                       // z reads complete
    {
        float bhn_s = dec_bhh[512 + gc];
        int pcol = (gc & ~31) | ((gc & 15) << 1) | ((gc >> 4) & 1);
        #pragma unroll
        for (int i = 0; i < 8; ++i) {
            int m = gm2 + 2 * i;
            s_hl[m * HL_LD + gc] = th[i];
            short4v q = { f2bf(arr[i]), f2bf(azz[i]), f2bf(ann[i]), f2bf(bhn_s) };
            *(short4v*)(s_zp4 + (m * 256 + gc) * 4) = q;
            s_h[0][m * H_LD + pcol] = f2bf(th[i]);
        }
    }
    __syncthreads();                       // hidden staged

    float hpr[4][2];
    #pragma unroll
    for (int j = 0; j < 4; ++j) {
        hpr[j][0] = s_hl[(lgrp * 4 + j) * HL_LD + colb];
        hpr[j][1] = s_hl[(lgrp * 4 + j) * HL_LD + colb + 16];
    }

    const int vcol = wv * 16 + l15;
    const int orow = (vcol < VOCAB) ? vcol : (VOCAB - 1);
    float ob = (wv < 7 && vcol < VOCAB) ? out_b[vcol] : 0.0f;
    const f32x4 z4 = {0.f, 0.f, 0.f, 0.f};

    #pragma unroll 1
    for (int t = 0; t < TT; ++t) {
        const short* rh = s_h[t & 1];
        short* wh2 = s_h[(t + 1) & 1];

        f32x4 acc[3][2];
        #pragma unroll
        for (int g = 0; g < 3; ++g) { acc[g][0] = z4; acc[g][1] = z4; }
        f32x4 aco = z4;

        #pragma unroll
        for (int ks = 0; ks < 8; ++ks) {
            bf16x8 a = *(const bf16x8*)(rh + l15 * H_LD + ks * 32 + lgrp * 8);
            #pragma unroll
            for (int g = 0; g < 3; ++g) {
                acc[g][0] = __builtin_amdgcn_mfma_f32_16x16x32_bf16(a, Wreg[g][0][ks], acc[g][0], 0, 0, 0);
                acc[g][1] = __builtin_amdgcn_mfma_f32_16x16x32_bf16(a, Wreg[g][1][ks], acc[g][1], 0, 0, 0);
            }
            if (wv < 7) {
                bf16x8 wo = *(const bf16x8*)(s_outw + orow * 512 + ((ks * 64 + lgrp * 16) ^ ((orow & 7) << 4)));
                aco = __builtin_amdgcn_mfma_f32_16x16x32_bf16(a, wo, aco, 0, 0, 0);
            }
        }

        if (t > 0 && wv < 7 && vcol < VOCAB) {
            size_t base = (size_t)(bbase + lgrp * 4) * LROW + (size_t)(t - 1) * VOCAB + vcol;
            #pragma unroll
            for (int j = 0; j < 4; ++j) out[base + (size_t)j * LROW] = aco[j] + ob;
        }

        #pragma unroll
        for (int j = 0; j < 4; ++j) {
            const int row = lgrp * 4 + j;
            short4v q0 = *(const short4v*)(s_zp4 + (row * 256 + colb) * 4);
            short4v q1 = *(const short4v*)(s_zp4 + (row * 256 + colb + 16) * 4);
            unsigned wpack = 0;
            #pragma unroll
            for (int cg = 0; cg < 2; ++cg) {
                short4v q = cg ? q1 : q0;
                float rg = sigf(acc[0][cg][j] + bf2f(q[0]));
                float zg = sigf(acc[1][cg][j] + bf2f(q[1]));
                float n  = tanh_f(bf2f(q[2]) + rg * (acc[2][cg][j] + bf2f(q[3])));
                float h  = (1.0f - zg) * n + zg * hpr[j][cg];
                hpr[j][cg] = h;
                wpack |= ((unsigned)(unsigned short)f2bf(h)) << (16 * cg);
            }
            *(unsigned*)(wh2 + row * H_LD + wv * 32 + 2 * l15) = wpack;
        }
        __syncthreads();
    }

    // final vocab projection from h_128 (in s_h[0] since TT is even)
    if (wv < 7) {
        const short* rh = s_h[0];
        f32x4 aco = z4;
        #pragma unroll
        for (int ks = 0; ks < 8; ++ks) {
            bf16x8 a  = *(const bf16x8*)(rh + l15 * H_LD + ks * 32 + lgrp * 8);
            bf16x8 wo = *(const bf16x8*)(s_outw + orow * 512 + ((ks * 64 + lgrp * 16) ^ ((orow & 7) << 4)));
            aco = __builtin_amdgcn_mfma_f32_16x16x32_bf16(a, wo, aco, 0, 0, 0);
        }
        if (vcol < VOCAB) {
            size_t base = (size_t)(bbase + lgrp * 4) * LROW + (size_t)(TT - 1) * VOCAB + vcol;
            #pragma unroll
            for (int j = 0; j < 4; ++j) out[base + (size_t)j * LROW] = aco[j] + ob;
        }
    }
}

extern "C" void kernel_launch(void* const* d_in, const int* in_sizes, int n_in,
                              void* d_out, int out_size, void* d_ws, size_t ws_size,
                              hipStream_t stream) {
    const int*   x       = (const int*)  d_in[0];
    const float* eps     = (const float*)d_in[1];
    const float* emb     = (const float*)d_in[2];
    const float* enc_Wih = (const float*)d_in[3];
    const float* enc_Whh = (const float*)d_in[4];
    const float* enc_bih = (const float*)d_in[5];
    const float* enc_bhh = (const float*)d_in[6];
    const float* mu_W    = (const float*)d_in[7];
    const float* mu_b    = (const float*)d_in[8];
    const float* lv_W    = (const float*)d_in[9];
    const float* lv_b    = (const float*)d_in[10];
    const float* di_W    = (const float*)d_in[11];
    const float* di_b    = (const float*)d_in[12];
    const float* dec_Wih = (const float*)d_in[13];
    const float* dec_Whh = (const float*)d_in[14];
    const float* dec_bih = (const float*)d_in[15];
    const float* dec_bhh = (const float*)d_in[16];
    const float* out_W   = (const float*)d_in[17];
    const float* out_b   = (const float*)d_in[18];
    float* out = (float*)d_out;
    float* PT  = (float*)d_ws;   // [100][768] f32

    pt_kernel<<<VOCAB, 256, 0, stream>>>(emb, enc_Wih, enc_bih, enc_bhh, PT);
    enc_kernel<<<BB / 16, 512, 0, stream>>>(x, PT, enc_Whh, enc_bhh, out);
    dec_kernel<<<BB / 16, 512, 0, stream>>>(eps, mu_W, mu_b, lv_W, lv_b,
        di_W, di_b, dec_Wih, dec_Whh, dec_bih, dec_bhh, out_W, out_b, out);
}

// Round 4
// 1133.571 us; speedup vs baseline: 1.2197x; 1.1312x over previous
//
#include <hip/hip_runtime.h>
#include <hip/hip_bf16.h>

#define VOCAB 100
#define EDIM  128
#define HDIM  256
#define LDIM  64
#define G3    768
#define TT    128
#define BB    4096
#define LROW  (TT * VOCAB)
#define H_LD  264            // shorts per row in h buffers (256 + 8 pad)
#define HBUF  (16 * H_LD)
#define HL_LD 260            // floats per row in dec f32 scratch

typedef float f32x4  __attribute__((ext_vector_type(4)));
typedef short bf16x8 __attribute__((ext_vector_type(8)));

__device__ __forceinline__ short f2bf(float f) {
    unsigned u = __builtin_bit_cast(unsigned, f);
    u += 0x7FFFu + ((u >> 16) & 1u);
    return (short)(u >> 16);
}
__device__ __forceinline__ float bf2f(short s) {
    unsigned u = ((unsigned)(unsigned short)s) << 16;
    return __builtin_bit_cast(float, u);
}
__device__ __forceinline__ float sigf(float x)   { return 1.0f / (1.0f + __expf(-x)); }
__device__ __forceinline__ float tanh_f(float x) { return 2.0f / (1.0f + __expf(-2.0f * x)) - 1.0f; }

// B-fragment loader for the K-permuted h layout (see R3; verified passing).
__device__ __forceinline__ bf16x8 load_bfragK(const float* __restrict__ W, int outcol, int ks, int lgrp) {
    const float* p = W + outcol * HDIM + ks * 32 + lgrp * 4;
    float4 f0 = *(const float4*)p;
    float4 f1 = *(const float4*)(p + 16);
    bf16x8 w;
    w[0] = f2bf(f0.x); w[1] = f2bf(f1.x); w[2] = f2bf(f0.y); w[3] = f2bf(f1.y);
    w[4] = f2bf(f0.z); w[5] = f2bf(f1.z); w[6] = f2bf(f0.w); w[7] = f2bf(f1.w);
    return w;
}

// ---------------- prep: PT2[v][g] = enc_Wih @ emb[v] + enc_bih + (g<512 ? enc_bhh : 0) ----------------
__global__ void pt_kernel(const float* __restrict__ emb, const float* __restrict__ Wih,
                          const float* __restrict__ bih, const float* __restrict__ bhh,
                          float* __restrict__ PT) {
    int v = blockIdx.x;
    __shared__ float se[EDIM];
    for (int e = threadIdx.x; e < EDIM; e += blockDim.x) se[e] = emb[v * EDIM + e];
    __syncthreads();
    for (int g = threadIdx.x; g < G3; g += blockDim.x) {
        const float* wr = Wih + g * EDIM;
        float acc = bih[g] + (g < 512 ? bhh[g] : 0.0f);
        #pragma unroll 8
        for (int e = 0; e < EDIM; ++e) acc += se[e] * wr[e];
        PT[v * G3 + g] = acc;
    }
}

// ===================================================================
// ENCODER: 5 weight tiles in regs + 1 in LDS (kills spill), hi/lo bf16 h.
// ===================================================================
__global__ __launch_bounds__(512, 2) void enc_kernel(
    const int* __restrict__ x, const float* __restrict__ PT2,
    const float* __restrict__ Whh, const float* __restrict__ bhh,
    float* __restrict__ out)
{
    __shared__ short s_h[2][2][HBUF];      // 33792 B
    __shared__ int s_tok[16 * TT];         // 8192 B
    __shared__ __attribute__((aligned(16))) short s_wlds[8 * 8 * 64 * 8];  // 65536 B

    const int tid  = threadIdx.x;
    const int lane = tid & 63;
    const int wv   = tid >> 6;
    const int l15  = lane & 15;
    const int lgrp = lane >> 4;
    const int bbase = blockIdx.x * 16;
    const int colb = wv * 32 + l15;

    for (int i = tid; i < 16 * TT; i += 512) s_tok[i] = x[bbase * TT + i];

    // 5 register tiles: (g,cg) = (0,0)(0,1)(1,0)(1,1)(2,0); tile (2,1) -> LDS
    bf16x8 Wreg[5][8];
    #pragma unroll
    for (int wi = 0; wi < 5; ++wi) {
        int g = wi >> 1, cg = wi & 1;
        #pragma unroll
        for (int ks = 0; ks < 8; ++ks)
            Wreg[wi][ks] = load_bfragK(Whh, g * 256 + colb + cg * 16, ks, lgrp);
    }
    const int w5b = wv * 4096 + lane * 8;
    #pragma unroll
    for (int ks = 0; ks < 8; ++ks) {
        bf16x8 w = load_bfragK(Whh, 512 + colb + 16, ks, lgrp);
        *(bf16x8*)(s_wlds + w5b + ks * 512) = w;
    }

    const float bhn0 = bhh[512 + colb];
    const float bhn1 = bhh[528 + colb];

    for (int i = tid; i < 2 * HBUF; i += 512) s_h[0][0][i] = 0;
    __syncthreads();

    const f32x4 z4 = {0.f, 0.f, 0.f, 0.f};

    #pragma unroll 1
    for (int t = 0; t < TT; ++t) {
        const short* rh = s_h[t & 1][0];
        const short* rl = s_h[t & 1][1];
        short* wh = s_h[(t + 1) & 1][0];
        short* wl = s_h[(t + 1) & 1][1];

        f32x4 acc[3][2];
        #pragma unroll
        for (int g = 0; g < 3; ++g) { acc[g][0] = z4; acc[g][1] = z4; }

        #pragma unroll
        for (int ks = 0; ks < 8; ++ks) {
            const int aoff = l15 * H_LD + ks * 32 + lgrp * 8;
            bf16x8 b5 = *(const bf16x8*)(s_wlds + w5b + ks * 512);
            bf16x8 ahi = *(const bf16x8*)(rh + aoff);
            acc[0][0] = __builtin_amdgcn_mfma_f32_16x16x32_bf16(ahi, Wreg[0][ks], acc[0][0], 0, 0, 0);
            acc[0][1] = __builtin_amdgcn_mfma_f32_16x16x32_bf16(ahi, Wreg[1][ks], acc[0][1], 0, 0, 0);
            acc[1][0] = __builtin_amdgcn_mfma_f32_16x16x32_bf16(ahi, Wreg[2][ks], acc[1][0], 0, 0, 0);
            acc[1][1] = __builtin_amdgcn_mfma_f32_16x16x32_bf16(ahi, Wreg[3][ks], acc[1][1], 0, 0, 0);
            acc[2][0] = __builtin_amdgcn_mfma_f32_16x16x32_bf16(ahi, Wreg[4][ks], acc[2][0], 0, 0, 0);
            acc[2][1] = __builtin_amdgcn_mfma_f32_16x16x32_bf16(ahi, b5,          acc[2][1], 0, 0, 0);
            bf16x8 alo = *(const bf16x8*)(rl + aoff);
            acc[0][0] = __builtin_amdgcn_mfma_f32_16x16x32_bf16(alo, Wreg[0][ks], acc[0][0], 0, 0, 0);
            acc[0][1] = __builtin_amdgcn_mfma_f32_16x16x32_bf16(alo, Wreg[1][ks], acc[0][1], 0, 0, 0);
            acc[1][0] = __builtin_amdgcn_mfma_f32_16x16x32_bf16(alo, Wreg[2][ks], acc[1][0], 0, 0, 0);
            acc[1][1] = __builtin_amdgcn_mfma_f32_16x16x32_bf16(alo, Wreg[3][ks], acc[1][1], 0, 0, 0);
            acc[2][0] = __builtin_amdgcn_mfma_f32_16x16x32_bf16(alo, Wreg[4][ks], acc[2][0], 0, 0, 0);
            acc[2][1] = __builtin_amdgcn_mfma_f32_16x16x32_bf16(alo, b5,          acc[2][1], 0, 0, 0);
        }

        #pragma unroll
        for (int j = 0; j < 4; ++j) {
            const int row = lgrp * 4 + j;
            const int tok = s_tok[row * TT + t];
            const float* p = PT2 + tok * G3 + colb;
            const int hoff = row * H_LD + wv * 32 + 2 * l15;
            unsigned hpi = *(const unsigned*)(rh + hoff);
            unsigned hpl = *(const unsigned*)(rl + hoff);
            float hp0 = bf2f((short)(hpi & 0xFFFF)) + bf2f((short)(hpl & 0xFFFF));
            float hp1 = bf2f((short)(hpi >> 16))    + bf2f((short)(hpl >> 16));
            unsigned whi = 0, wlo = 0;
            #pragma unroll
            for (int cg = 0; cg < 2; ++cg) {
                float xr = p[cg * 16], xz = p[256 + cg * 16], xn = p[512 + cg * 16];
                float rg = sigf(acc[0][cg][j] + xr);
                float zg = sigf(acc[1][cg][j] + xz);
                float hn = acc[2][cg][j] + (cg ? bhn1 : bhn0);
                float n  = tanh_f(xn + rg * hn);
                float hpv = cg ? hp1 : hp0;
                float h  = (1.0f - zg) * n + zg * hpv;
                if (t == TT - 1) out[(size_t)(bbase + row) * LROW + colb + cg * 16] = h;
                unsigned hhi = (unsigned)(unsigned short)f2bf(h);
                float rem = h - bf2f((short)hhi);
                unsigned hlo = (unsigned)(unsigned short)f2bf(rem);
                whi |= hhi << (16 * cg);
                wlo |= hlo << (16 * cg);
            }
            *(unsigned*)(wh + hoff) = whi;
            *(unsigned*)(wl + hoff) = wlo;
        }
        __syncthreads();
    }
}

// ===================================================================
// DECODER: 5+1 weight tiles, split zrz/zn gate precomputes, fused vocab proj.
// ===================================================================
#define D_OFF_ZRZ  16896                      // unsigned[16][258] = 16512
#define D_OFF_ZN   (D_OFF_ZRZ + 16512)        // short[16][264]    = 8448
#define D_OFF_OUTW (D_OFF_ZN + 8448)          // 51200 (16B aligned: 41856)
#define D_OFF_WLDS (D_OFF_OUTW + 51200)       // 65536 (16B aligned: 93056)
#define D_TOT      (D_OFF_WLDS + 65536)       // 158592

__global__ __launch_bounds__(512, 2) void dec_kernel(
    const float* __restrict__ eps,
    const float* __restrict__ mu_W, const float* __restrict__ mu_b,
    const float* __restrict__ lv_W, const float* __restrict__ lv_b,
    const float* __restrict__ di_W, const float* __restrict__ di_b,
    const float* __restrict__ dec_Wih, const float* __restrict__ dec_Whh,
    const float* __restrict__ dec_bih, const float* __restrict__ dec_bhh,
    const float* __restrict__ out_W, const float* __restrict__ out_b,
    float* __restrict__ out)
{
    __shared__ __attribute__((aligned(16))) unsigned char dsm[D_TOT];
    short*    s_hb   = (short*)(dsm);                 // 2 x HBUF h double-buffer
    unsigned* s_zrz  = (unsigned*)(dsm + D_OFF_ZRZ);
    short*    s_zn   = (short*)(dsm + D_OFF_ZN);
    unsigned char* s_outw = dsm + D_OFF_OUTW;
    short*    s_wlds = (short*)(dsm + D_OFF_WLDS);
    float*    s_hl   = (float*)(dsm + D_OFF_WLDS);    // alias (prologue only)

    const int tid  = threadIdx.x;
    const int lane = tid & 63;
    const int wv   = tid >> 6;
    const int l15  = lane & 15;
    const int lgrp = lane >> 4;
    const int bbase = blockIdx.x * 16;
    const int colb = wv * 32 + l15;
    const int gc  = tid & 255;
    const int gm2 = tid >> 8;

    // h_last stash -> LDS (alias region; wlds staged later)
    for (int i = tid; i < 16 * HDIM; i += 512) {
        int m = i >> 8, c = i & 255;
        s_hl[m * HL_LD + c] = out[(size_t)(bbase + m) * LROW + c];
    }

    bf16x8 Wreg[5][8];
    #pragma unroll
    for (int wi = 0; wi < 5; ++wi) {
        int g = wi >> 1, cg = wi & 1;
        #pragma unroll
        for (int ks = 0; ks < 8; ++ks)
            Wreg[wi][ks] = load_bfragK(dec_Whh, g * 256 + colb + cg * 16, ks, lgrp);
    }
    __syncthreads();

    // ---- mu / logvar / z ----
    float z0 = 0.f, z1 = 0.f;
    {
        const size_t MU_OFF = (size_t)BB * TT * VOCAB;
        const size_t LV_OFF = MU_OFF + (size_t)BB * LDIM;
        #pragma unroll
        for (int oo = 0; oo < 2; ++oo) {
            int o = tid * 2 + oo;
            int m = o >> 6, j = o & 63;
            const float* mwr = mu_W + j * HDIM;
            const float* lwr = lv_W + j * HDIM;
            float am = mu_b[j], al = lv_b[j];
            #pragma unroll 4
            for (int k = 0; k < HDIM; ++k) { float hv = s_hl[m * HL_LD + k]; am += hv * mwr[k]; al += hv * lwr[k]; }
            size_t bo = (size_t)(bbase + m) * LDIM + j;
            out[MU_OFF + bo] = am;
            out[LV_OFF + bo] = al;
            float zv = am + eps[bo] * __expf(0.5f * al);
            if (oo == 0) z0 = zv; else z1 = zv;
        }
    }
    __syncthreads();                       // all h_last reads done
    {
        int o0 = tid * 2;
        s_hl[(o0 >> 6) * HL_LD + (o0 & 63)] = z0;
        int o1 = o0 + 1;
        s_hl[(o1 >> 6) * HL_LD + (o1 & 63)] = z1;
        // stage out_W: K-permuted + XOR-swizzled bf16
        for (int idx = tid; idx < VOCAB * HDIM; idx += 512) {
            int r = idx >> 8, kp = idx & 255;
            int kl = (kp & ~31) | ((kp & 1) << 4) | ((kp & 31) >> 1);
            *(short*)(s_outw + r * 512 + ((2 * kp) ^ ((r & 7) << 4))) = f2bf(out_W[r * 256 + kl]);
        }
    }
    __syncthreads();                       // z + out_W staged

    float th[8], arr[8], azz[8], ann[8];
    {
        float ah[8];
        float dib = di_b[gc];
        float bir = dec_bih[gc], biz = dec_bih[gc + 256], bin_ = dec_bih[gc + 512];
        #pragma unroll
        for (int i = 0; i < 8; ++i) { ah[i] = dib; arr[i] = bir; azz[i] = biz; ann[i] = bin_; }
        const float* w0 = di_W + gc * LDIM;
        const float* w1 = dec_Wih + gc * LDIM;
        const float* w2 = dec_Wih + (gc + 256) * LDIM;
        const float* w3 = dec_Wih + (gc + 512) * LDIM;
        #pragma unroll 2
        for (int j = 0; j < LDIM; ++j) {
            float a0 = w0[j], a1 = w1[j], a2 = w2[j], a3 = w3[j];
            #pragma unroll
            for (int i = 0; i < 8; ++i) {
                float zv = s_hl[(gm2 + 2 * i) * HL_LD + j];
                ah[i] += zv * a0; arr[i] += zv * a1; azz[i] += zv * a2; ann[i] += zv * a3;
            }
        }
        float bhr = dec_bhh[gc], bhz = dec_bhh[gc + 256];
        #pragma unroll
        for (int i = 0; i < 8; ++i) {
            th[i] = tanh_f(ah[i]);
            arr[i] += bhr;
            azz[i] += bhz;
        }
    }
    __syncthreads();                       // z reads complete
    {
        int pcol = (gc & ~31) | ((gc & 15) << 1) | ((gc >> 4) & 1);
        #pragma unroll
        for (int i = 0; i < 8; ++i) {
            int m = gm2 + 2 * i;
            s_hl[m * HL_LD + gc] = th[i];  // f32 h0 for hpr init
            s_zrz[m * 258 + gc] = (unsigned)(unsigned short)f2bf(arr[i]) |
                                  (((unsigned)(unsigned short)f2bf(azz[i])) << 16);
            s_zn[m * 264 + gc] = f2bf(ann[i]);
            s_hb[m * H_LD + pcol] = f2bf(th[i]);   // buf0
        }
    }
    __syncthreads();                       // th/zrz/zn/h0 staged

    float hpr[4][2];
    #pragma unroll
    for (int j = 0; j < 4; ++j) {
        hpr[j][0] = s_hl[(lgrp * 4 + j) * HL_LD + colb];
        hpr[j][1] = s_hl[(lgrp * 4 + j) * HL_LD + colb + 16];
    }
    __syncthreads();                       // s_hl dead -> stage wlds (tile g=2,cg=1)
    const int w5b = wv * 4096 + lane * 8;
    #pragma unroll
    for (int ks = 0; ks < 8; ++ks) {
        bf16x8 w = load_bfragK(dec_Whh, 512 + colb + 16, ks, lgrp);
        *(bf16x8*)(s_wlds + w5b + ks * 512) = w;
    }
    const float bhn0 = dec_bhh[512 + colb];
    const float bhn1 = dec_bhh[528 + colb];
    __syncthreads();

    const int vcol = wv * 16 + l15;
    const int orow = (vcol < VOCAB) ? vcol : (VOCAB - 1);
    float ob = (wv < 7 && vcol < VOCAB) ? out_b[vcol] : 0.0f;
    const f32x4 z4 = {0.f, 0.f, 0.f, 0.f};

    #pragma unroll 1
    for (int t = 0; t < TT; ++t) {
        const short* rh = s_hb + (t & 1) * HBUF;
        short* wh2 = s_hb + ((t + 1) & 1) * HBUF;

        f32x4 acc[3][2];
        #pragma unroll
        for (int g = 0; g < 3; ++g) { acc[g][0] = z4; acc[g][1] = z4; }
        f32x4 aco = z4;

        #pragma unroll
        for (int ks = 0; ks < 8; ++ks) {
            bf16x8 b5 = *(const bf16x8*)(s_wlds + w5b + ks * 512);
            bf16x8 a = *(const bf16x8*)(rh + l15 * H_LD + ks * 32 + lgrp * 8);
            acc[0][0] = __builtin_amdgcn_mfma_f32_16x16x32_bf16(a, Wreg[0][ks], acc[0][0], 0, 0, 0);
            acc[0][1] = __builtin_amdgcn_mfma_f32_16x16x32_bf16(a, Wreg[1][ks], acc[0][1], 0, 0, 0);
            acc[1][0] = __builtin_amdgcn_mfma_f32_16x16x32_bf16(a, Wreg[2][ks], acc[1][0], 0, 0, 0);
            acc[1][1] = __builtin_amdgcn_mfma_f32_16x16x32_bf16(a, Wreg[3][ks], acc[1][1], 0, 0, 0);
            acc[2][0] = __builtin_amdgcn_mfma_f32_16x16x32_bf16(a, Wreg[4][ks], acc[2][0], 0, 0, 0);
            acc[2][1] = __builtin_amdgcn_mfma_f32_16x16x32_bf16(a, b5,          acc[2][1], 0, 0, 0);
            if (wv < 7) {
                bf16x8 wo = *(const bf16x8*)(s_outw + orow * 512 + ((ks * 64 + lgrp * 16) ^ ((orow & 7) << 4)));
                aco = __builtin_amdgcn_mfma_f32_16x16x32_bf16(a, wo, aco, 0, 0, 0);
            }
        }

        if (t > 0 && wv < 7 && vcol < VOCAB) {
            size_t base = (size_t)(bbase + lgrp * 4) * LROW + (size_t)(t - 1) * VOCAB + vcol;
            #pragma unroll
            for (int j = 0; j < 4; ++j) out[base + (size_t)j * LROW] = aco[j] + ob;
        }

        #pragma unroll
        for (int j = 0; j < 4; ++j) {
            const int row = lgrp * 4 + j;
            unsigned rz0 = s_zrz[row * 258 + colb];
            unsigned rz1 = s_zrz[row * 258 + colb + 16];
            float n0 = bf2f(s_zn[row * 264 + colb]);
            float n1 = bf2f(s_zn[row * 264 + colb + 16]);
            unsigned wpack = 0;
            #pragma unroll
            for (int cg = 0; cg < 2; ++cg) {
                unsigned rz = cg ? rz1 : rz0;
                float rg = sigf(acc[0][cg][j] + bf2f((short)(rz & 0xFFFF)));
                float zg = sigf(acc[1][cg][j] + bf2f((short)(rz >> 16)));
                float n  = tanh_f((cg ? n1 : n0) + rg * (acc[2][cg][j] + (cg ? bhn1 : bhn0)));
                float h  = (1.0f - zg) * n + zg * hpr[j][cg];
                hpr[j][cg] = h;
                wpack |= ((unsigned)(unsigned short)f2bf(h)) << (16 * cg);
            }
            *(unsigned*)(wh2 + row * H_LD + wv * 32 + 2 * l15) = wpack;
        }
        __syncthreads();
    }

    // final vocab projection from h_128 (in buf 0 since TT is even)
    if (wv < 7) {
        const short* rh = s_hb;
        f32x4 aco = z4;
        #pragma unroll
        for (int ks = 0; ks < 8; ++ks) {
            bf16x8 a  = *(const bf16x8*)(rh + l15 * H_LD + ks * 32 + lgrp * 8);
            bf16x8 wo = *(const bf16x8*)(s_outw + orow * 512 + ((ks * 64 + lgrp * 16) ^ ((orow & 7) << 4)));
            aco = __builtin_amdgcn_mfma_f32_16x16x32_bf16(a, wo, aco, 0, 0, 0);
        }
        if (vcol < VOCAB) {
            size_t base = (size_t)(bbase + lgrp * 4) * LROW + (size_t)(TT - 1) * VOCAB + vcol;
            #pragma unroll
            for (int j = 0; j < 4; ++j) out[base + (size_t)j * LROW] = aco[j] + ob;
        }
    }
}

extern "C" void kernel_launch(void* const* d_in, const int* in_sizes, int n_in,
                              void* d_out, int out_size, void* d_ws, size_t ws_size,
                              hipStream_t stream) {
    const int*   x       = (const int*)  d_in[0];
    const float* eps     = (const float*)d_in[1];
    const float* emb     = (const float*)d_in[2];
    const float* enc_Wih = (const float*)d_in[3];
    const float* enc_Whh = (const float*)d_in[4];
    const float* enc_bih = (const float*)d_in[5];
    const float* enc_bhh = (const float*)d_in[6];
    const float* mu_W    = (const float*)d_in[7];
    const float* mu_b    = (const float*)d_in[8];
    const float* lv_W    = (const float*)d_in[9];
    const float* lv_b    = (const float*)d_in[10];
    const float* di_W    = (const float*)d_in[11];
    const float* di_b    = (const float*)d_in[12];
    const float* dec_Wih = (const float*)d_in[13];
    const float* dec_Whh = (const float*)d_in[14];
    const float* dec_bih = (const float*)d_in[15];
    const float* dec_bhh = (const float*)d_in[16];
    const float* out_W   = (const float*)d_in[17];
    const float* out_b   = (const float*)d_in[18];
    float* out = (float*)d_out;
    float* PT  = (float*)d_ws;   // [100][768] f32

    pt_kernel<<<VOCAB, 256, 0, stream>>>(emb, enc_Wih, enc_bih, enc_bhh, PT);
    enc_kernel<<<BB / 16, 512, 0, stream>>>(x, PT, enc_Whh, enc_bhh, out);
    dec_kernel<<<BB / 16, 512, 0, stream>>>(eps, mu_W, mu_b, lv_W, lv_b,
        di_W, di_b, dec_Wih, dec_Whh, dec_bih, dec_bhh, out_W, out_b, out);
}

// Round 5
// 966.341 us; speedup vs baseline: 1.4308x; 1.1731x over previous
//
#include <hip/hip_runtime.h>
#include <hip/hip_bf16.h>

#define VOCAB 100
#define EDIM  128
#define HDIM  256
#define LDIM  64
#define G3    768
#define TT    128
#define BB    4096
#define LROW  (TT * VOCAB)
#define H_LD  264            // halfs per h-row: 256 + 8 pad -> row stride 528B = 16 mod 128
#define ZP_LD 17             // f16x4 units per zp col (16 rows + 1 pad) -> 136B stride

typedef float    f32x4 __attribute__((ext_vector_type(4)));
typedef _Float16 f16x8 __attribute__((ext_vector_type(8)));
typedef _Float16 f16x4 __attribute__((ext_vector_type(4)));

__device__ __forceinline__ float sigf(float x) {
    return __builtin_amdgcn_rcpf(1.0f + __expf(-x));
}
__device__ __forceinline__ float tanh_f(float x) {
    return 2.0f * __builtin_amdgcn_rcpf(1.0f + __expf(-2.0f * x)) - 1.0f;
}

// B fragment, linear K: lane(l15=col, lgrp) elem e holds B[k=ks*32+lgrp*8+e][outcol]
__device__ __forceinline__ f16x8 ld_bfrag(const float* __restrict__ W, int outcol, int ks, int lgrp) {
    const float* p = W + outcol * HDIM + ks * 32 + lgrp * 8;
    float4 a = *(const float4*)p;
    float4 b = *(const float4*)(p + 4);
    f16x8 w = {(_Float16)a.x, (_Float16)a.y, (_Float16)a.z, (_Float16)a.w,
               (_Float16)b.x, (_Float16)b.y, (_Float16)b.z, (_Float16)b.w};
    return w;
}

// ---------------- prep: PT2[v][g] = enc_Wih@emb[v] + enc_bih + (g<512 ? enc_bhh : 0), f16 ----------------
__global__ void pt_kernel(const float* __restrict__ emb, const float* __restrict__ Wih,
                          const float* __restrict__ bih, const float* __restrict__ bhh,
                          _Float16* __restrict__ PT) {
    int v = blockIdx.x;
    __shared__ float se[EDIM];
    for (int e = threadIdx.x; e < EDIM; e += blockDim.x) se[e] = emb[v * EDIM + e];
    __syncthreads();
    for (int g = threadIdx.x; g < G3; g += blockDim.x) {
        const float* wr = Wih + g * EDIM;
        float acc = bih[g] + (g < 512 ? bhh[g] : 0.0f);
        #pragma unroll 8
        for (int e = 0; e < EDIM; ++e) acc += se[e] * wr[e];
        PT[v * G3 + g] = (_Float16)acc;
    }
}

// ===================================================================
// ENCODER: 1024 thr / 16 waves; wave wv owns output cols wv*16..+16 for
// all 3 gates (96 weight VGPRs). h_prev lives in lane registers (f32).
// ===================================================================
__global__ __launch_bounds__(1024, 4) void enc_kernel(
    const int* __restrict__ x, const _Float16* __restrict__ PT2,
    const float* __restrict__ Whh, const float* __restrict__ bhh,
    float* __restrict__ out)
{
    __shared__ _Float16 s_h[2][16 * H_LD];   // 2 x 8448 B
    __shared__ int s_tok[16 * TT];           // 8192 B

    const int tid  = threadIdx.x;
    const int lane = tid & 63;
    const int wv   = tid >> 6;               // 0..15
    const int l15  = lane & 15;
    const int lgrp = lane >> 4;
    const int bbase = blockIdx.x * 16;
    const int col  = wv * 16 + l15;          // this lane's output/gate column

    for (int i = tid; i < 16 * TT; i += 1024) s_tok[i] = x[bbase * TT + i];

    f16x8 Breg[3][8];
    #pragma unroll
    for (int g = 0; g < 3; ++g)
        #pragma unroll
        for (int ks = 0; ks < 8; ++ks)
            Breg[g][ks] = ld_bfrag(Whh, g * 256 + col, ks, lgrp);

    const float bhn = bhh[512 + col];
    float hst[4] = {0.f, 0.f, 0.f, 0.f};

    for (int i = tid; i < 16 * H_LD; i += 1024) s_h[0][i] = (_Float16)0.f;
    __syncthreads();

    const f32x4 z4 = {0.f, 0.f, 0.f, 0.f};

    #pragma unroll 1
    for (int t = 0; t < TT; ++t) {
        const _Float16* rh = s_h[t & 1];
        _Float16* wh = s_h[(t + 1) & 1];

        f32x4 a0 = z4, a1 = z4, a2 = z4;
        #pragma unroll
        for (int ks = 0; ks < 8; ++ks) {
            f16x8 a = *(const f16x8*)(rh + l15 * H_LD + ks * 32 + lgrp * 8);
            a0 = __builtin_amdgcn_mfma_f32_16x16x32_f16(a, Breg[0][ks], a0, 0, 0, 0);
            a1 = __builtin_amdgcn_mfma_f32_16x16x32_f16(a, Breg[1][ks], a1, 0, 0, 0);
            a2 = __builtin_amdgcn_mfma_f32_16x16x32_f16(a, Breg[2][ks], a2, 0, 0, 0);
        }
        #pragma unroll
        for (int j = 0; j < 4; ++j) {
            const int row = lgrp * 4 + j;
            const int tok = s_tok[row * TT + t];
            const _Float16* p = PT2 + tok * G3 + col;
            float xr = (float)p[0], xz = (float)p[256], xn = (float)p[512];
            float rg = sigf(a0[j] + xr);
            float zg = sigf(a1[j] + xz);
            float n  = tanh_f(xn + rg * (a2[j] + bhn));
            float h  = n + zg * (hst[j] - n);
            hst[j] = h;
            wh[row * H_LD + col] = (_Float16)h;
            if (t == TT - 1) out[(size_t)(bbase + row) * LROW + col] = h;
        }
        __syncthreads();
    }
}

// ===================================================================
// DECODER: 1024 thr / 16 waves; prologue (mu/lv/z/proj) + GRU loop with
// fused vocab projection (waves 0..6).
// ===================================================================
__global__ __launch_bounds__(1024, 4) void dec_kernel(
    const float* __restrict__ eps,
    const float* __restrict__ mu_W, const float* __restrict__ mu_b,
    const float* __restrict__ lv_W, const float* __restrict__ lv_b,
    const float* __restrict__ di_W, const float* __restrict__ di_b,
    const float* __restrict__ dec_Wih, const float* __restrict__ dec_Whh,
    const float* __restrict__ dec_bih, const float* __restrict__ dec_bhh,
    const float* __restrict__ out_W, const float* __restrict__ out_b,
    float* __restrict__ out)
{
    __shared__ _Float16 s_hb[2][16 * H_LD];                                 // 16896 B
    __shared__ f16x4 s_zp[256 * ZP_LD];                                     // 34816 B {r,z,n,_}
    __shared__ __attribute__((aligned(16))) unsigned char s_outw[VOCAB * 512]; // 51200 B f16 swizzled
    __shared__ float s_hl[16 * 260];                                        // 16640 B

    const int tid  = threadIdx.x;
    const int lane = tid & 63;
    const int wv   = tid >> 6;
    const int l15  = lane & 15;
    const int lgrp = lane >> 4;
    const int bbase = blockIdx.x * 16;
    const int col  = wv * 16 + l15;

    // h_last stash -> LDS; stage out_W (f16, XOR-swizzled)
    for (int i = tid; i < 16 * HDIM; i += 1024) {
        int m = i >> 8, c = i & 255;
        s_hl[m * 260 + c] = out[(size_t)(bbase + m) * LROW + c];
    }
    for (int idx = tid; idx < VOCAB * HDIM; idx += 1024) {
        int r = idx >> 8, k = idx & 255;
        _Float16 w = (_Float16)out_W[r * 256 + k];
        *(short*)(s_outw + r * 512 + ((2 * k) ^ ((r & 7) << 4))) = __builtin_bit_cast(short, w);
    }

    f16x8 Breg[3][8];
    #pragma unroll
    for (int g = 0; g < 3; ++g)
        #pragma unroll
        for (int ks = 0; ks < 8; ++ks)
            Breg[g][ks] = ld_bfrag(dec_Whh, g * 256 + col, ks, lgrp);
    __syncthreads();

    // ---- mu / logvar / z : one (m,j) per thread ----
    float zv;
    {
        const size_t MU_OFF = (size_t)BB * TT * VOCAB;
        const size_t LV_OFF = MU_OFF + (size_t)BB * LDIM;
        int m = tid >> 6, j = tid & 63;
        const float* mwr = mu_W + j * HDIM;
        const float* lwr = lv_W + j * HDIM;
        float am = mu_b[j], al = lv_b[j];
        #pragma unroll 4
        for (int k = 0; k < HDIM; ++k) { float hv = s_hl[m * 260 + k]; am += hv * mwr[k]; al += hv * lwr[k]; }
        size_t bo = (size_t)(bbase + m) * LDIM + j;
        out[MU_OFF + bo] = am;
        out[LV_OFF + bo] = al;
        zv = am + eps[bo] * __expf(0.5f * al);
    }
    __syncthreads();                     // all h_last reads done
    { int m = tid >> 6, j = tid & 63; s_hl[m * 260 + j] = zv; }
    __syncthreads();                     // z staged (cols 0..63)

    // ---- hidden = tanh(di_W z + di_b); zp = dec_Wih z + dec_bih (+bhh r,z) ----
    float th[4];
    {
        const int gc = tid & 255;
        const int gm = tid >> 8;         // 0..3 -> rows gm*4..+4
        float ah[4], ar[4], az[4], an[4];
        float dib = di_b[gc];
        float bir = dec_bih[gc], biz = dec_bih[gc + 256], bin_ = dec_bih[gc + 512];
        #pragma unroll
        for (int i = 0; i < 4; ++i) { ah[i] = dib; ar[i] = bir; az[i] = biz; an[i] = bin_; }
        const float* w0 = di_W + gc * LDIM;
        const float* w1 = dec_Wih + gc * LDIM;
        const float* w2 = dec_Wih + (gc + 256) * LDIM;
        const float* w3 = dec_Wih + (gc + 512) * LDIM;
        #pragma unroll 2
        for (int j = 0; j < LDIM; ++j) {
            float a0 = w0[j], a1 = w1[j], a2 = w2[j], a3 = w3[j];
            #pragma unroll
            for (int i = 0; i < 4; ++i) {
                float q = s_hl[(gm * 4 + i) * 260 + j];
                ah[i] += q * a0; ar[i] += q * a1; az[i] += q * a2; an[i] += q * a3;
            }
        }
        float bhr = dec_bhh[gc], bhz = dec_bhh[gc + 256];
        __syncthreads();                 // all z reads done before s_hl overwrite
        #pragma unroll
        for (int i = 0; i < 4; ++i) {
            int r = gm * 4 + i;
            th[i] = tanh_f(ah[i]);
            s_hl[r * 260 + gc] = th[i];
            f16x4 q = {(_Float16)(ar[i] + bhr), (_Float16)(az[i] + bhz), (_Float16)an[i], (_Float16)0.f};
            s_zp[gc * ZP_LD + r] = q;
            s_hb[0][r * H_LD + gc] = (_Float16)th[i];
        }
    }
    __syncthreads();                     // th/zp/h0 staged

    float hpr[4];
    #pragma unroll
    for (int j = 0; j < 4; ++j) hpr[j] = s_hl[(lgrp * 4 + j) * 260 + col];

    const float bhn = dec_bhh[512 + col];
    const int vcol = wv * 16 + l15;
    const int orow = (vcol < VOCAB) ? vcol : (VOCAB - 1);
    const float ob = (wv < 7 && vcol < VOCAB) ? out_b[vcol] : 0.0f;
    const f32x4 z4 = {0.f, 0.f, 0.f, 0.f};

    #pragma unroll 1
    for (int t = 0; t < TT; ++t) {
        const _Float16* rh = s_hb[t & 1];
        _Float16* wh = s_hb[(t + 1) & 1];

        f32x4 a0 = z4, a1 = z4, a2 = z4, aco = z4;
        #pragma unroll
        for (int ks = 0; ks < 8; ++ks) {
            f16x8 a = *(const f16x8*)(rh + l15 * H_LD + ks * 32 + lgrp * 8);
            a0 = __builtin_amdgcn_mfma_f32_16x16x32_f16(a, Breg[0][ks], a0, 0, 0, 0);
            a1 = __builtin_amdgcn_mfma_f32_16x16x32_f16(a, Breg[1][ks], a1, 0, 0, 0);
            a2 = __builtin_amdgcn_mfma_f32_16x16x32_f16(a, Breg[2][ks], a2, 0, 0, 0);
            if (wv < 7) {
                f16x8 wo = *(const f16x8*)(s_outw + orow * 512 + ((ks * 64 + lgrp * 16) ^ ((orow & 7) << 4)));
                aco = __builtin_amdgcn_mfma_f32_16x16x32_f16(a, wo, aco, 0, 0, 0);
            }
        }

        if (t > 0 && wv < 7 && vcol < VOCAB) {   // logits[:, t-1, :] from h_t
            size_t base = (size_t)(bbase + lgrp * 4) * LROW + (size_t)(t - 1) * VOCAB + vcol;
            #pragma unroll
            for (int j = 0; j < 4; ++j) out[base + (size_t)j * LROW] = aco[j] + ob;
        }

        #pragma unroll
        for (int j = 0; j < 4; ++j) {
            const int row = lgrp * 4 + j;
            f16x4 q = s_zp[col * ZP_LD + lgrp * 4 + j];
            float rg = sigf(a0[j] + (float)q[0]);
            float zg = sigf(a1[j] + (float)q[1]);
            float n  = tanh_f((float)q[2] + rg * (a2[j] + bhn));
            float h  = n + zg * (hpr[j] - n);
            hpr[j] = h;
            wh[row * H_LD + col] = (_Float16)h;
        }
        __syncthreads();
    }

    // logits[:, 127, :] from h_128 (buf 0, TT even)
    if (wv < 7) {
        const _Float16* rh = s_hb[0];
        f32x4 aco = z4;
        #pragma unroll
        for (int ks = 0; ks < 8; ++ks) {
            f16x8 a  = *(const f16x8*)(rh + l15 * H_LD + ks * 32 + lgrp * 8);
            f16x8 wo = *(const f16x8*)(s_outw + orow * 512 + ((ks * 64 + lgrp * 16) ^ ((orow & 7) << 4)));
            aco = __builtin_amdgcn_mfma_f32_16x16x32_f16(a, wo, aco, 0, 0, 0);
        }
        if (vcol < VOCAB) {
            size_t base = (size_t)(bbase + lgrp * 4) * LROW + (size_t)(TT - 1) * VOCAB + vcol;
            #pragma unroll
            for (int j = 0; j < 4; ++j) out[base + (size_t)j * LROW] = aco[j] + ob;
        }
    }
}

extern "C" void kernel_launch(void* const* d_in, const int* in_sizes, int n_in,
                              void* d_out, int out_size, void* d_ws, size_t ws_size,
                              hipStream_t stream) {
    const int*   x       = (const int*)  d_in[0];
    const float* eps     = (const float*)d_in[1];
    const float* emb     = (const float*)d_in[2];
    const float* enc_Wih = (const float*)d_in[3];
    const float* enc_Whh = (const float*)d_in[4];
    const float* enc_bih = (const float*)d_in[5];
    const float* enc_bhh = (const float*)d_in[6];
    const float* mu_W    = (const float*)d_in[7];
    const float* mu_b    = (const float*)d_in[8];
    const float* lv_W    = (const float*)d_in[9];
    const float* lv_b    = (const float*)d_in[10];
    const float* di_W    = (const float*)d_in[11];
    const float* di_b    = (const float*)d_in[12];
    const float* dec_Wih = (const float*)d_in[13];
    const float* dec_Whh = (const float*)d_in[14];
    const float* dec_bih = (const float*)d_in[15];
    const float* dec_bhh = (const float*)d_in[16];
    const float* out_W   = (const float*)d_in[17];
    const float* out_b   = (const float*)d_in[18];
    float* out = (float*)d_out;
    _Float16* PT = (_Float16*)d_ws;   // [100][768] f16 = 153600 B

    pt_kernel<<<VOCAB, 256, 0, stream>>>(emb, enc_Wih, enc_bih, enc_bhh, PT);
    enc_kernel<<<BB / 16, 1024, 0, stream>>>(x, PT, enc_Whh, enc_bhh, out);
    dec_kernel<<<BB / 16, 1024, 0, stream>>>(eps, mu_W, mu_b, lv_W, lv_b,
        di_W, di_b, dec_Wih, dec_Whh, dec_bih, dec_bhh, out_W, out_b, out);
}